// Round 5
// baseline (558.270 us; speedup 1.0000x reference)
//
#include <hip/hip_runtime.h>

// Problem constants
#define EPS 1e-5f
#define B_ 4
#define N_ 8192
#define D_ 1024
#define H_ 8
#define HD_ 128
#define M_TOT 32768   // B*N
#define NQKV 3072     // 3*D

typedef __bf16 bf16x8 __attribute__((ext_vector_type(8)));
typedef float f32x4 __attribute__((ext_vector_type(4)));

__device__ __forceinline__ float bf2f(unsigned short u) {
    unsigned int v = ((unsigned int)u) << 16;
    return __uint_as_float(v);
}
__device__ __forceinline__ unsigned short f2bf(float f) {
    unsigned int u = __float_as_uint(f);
    u += 0x7fffu + ((u >> 16) & 1u);   // RNE
    return (unsigned short)(u >> 16);
}

// fast activations: v_exp_f32 + v_rcp_f32 (~1e-6 rel err, saturates correctly)
__device__ __forceinline__ float fast_sigmoid(float v) {
    return __builtin_amdgcn_rcpf(1.0f + __expf(-v));
}
__device__ __forceinline__ float fast_tanh(float v) {
    return 1.0f - 2.0f * __builtin_amdgcn_rcpf(1.0f + __expf(2.0f * v));
}

// async global->LDS, 16B per lane; LDS dest is wave-uniform base + lane*16
__device__ __forceinline__ void gl_lds16(const void* g, void* l) {
    __builtin_amdgcn_global_load_lds(
        (const __attribute__((address_space(1))) unsigned int*)g,
        (__attribute__((address_space(3))) unsigned int*)l, 16, 0, 0);
}

// ---------------- Kernel 1: LayerNorm -> bf16 xn [32768][1024] ----------------
// 256 threads = 4 waves; each wave owns one row (16 elems/lane, shfl reduce,
// no LDS, no barriers). Grid 8192.
__global__ __launch_bounds__(256) void ln_kernel(const float* __restrict__ x,
                                                 const float* __restrict__ gamma,
                                                 const float* __restrict__ beta,
                                                 unsigned short* __restrict__ xn) {
    const int row = blockIdx.x * 4 + (threadIdx.x >> 6);
    const int t = threadIdx.x & 63;   // lane
    const float* xr = x + (size_t)row * D_;
    float4 xv[4];
    #pragma unroll
    for (int i = 0; i < 4; i++) xv[i] = ((const float4*)xr)[i * 64 + t];
    float s = 0.0f, s2 = 0.0f;
    #pragma unroll
    for (int i = 0; i < 4; i++) {
        s  += xv[i].x + xv[i].y + xv[i].z + xv[i].w;
        s2 += xv[i].x * xv[i].x + xv[i].y * xv[i].y
            + xv[i].z * xv[i].z + xv[i].w * xv[i].w;
    }
    #pragma unroll
    for (int off = 32; off > 0; off >>= 1) {
        s  += __shfl_down(s, off);
        s2 += __shfl_down(s2, off);
    }
    s = __shfl(s, 0);
    s2 = __shfl(s2, 0);
    const float mu = s * (1.0f / D_);
    const float var = s2 * (1.0f / D_) - mu * mu;
    const float rs = rsqrtf(var + EPS);
    unsigned short* xo = xn + (size_t)row * D_;
    #pragma unroll
    for (int i = 0; i < 4; i++) {
        float4 g  = ((const float4*)gamma)[i * 64 + t];
        float4 bt = ((const float4*)beta)[i * 64 + t];
        ushort4 o;
        o.x = f2bf((xv[i].x - mu) * rs * g.x + bt.x);
        o.y = f2bf((xv[i].y - mu) * rs * g.y + bt.y);
        o.z = f2bf((xv[i].z - mu) * rs * g.z + bt.z);
        o.w = f2bf((xv[i].w - mu) * rs * g.w + bt.w);
        ((ushort4*)xo)[i * 64 + t] = o;
    }
}

// ---------------- Kernel 2: transpose+cast w [1024][3072] -> wT bf16 [3072][1024]
__global__ __launch_bounds__(256) void wt_kernel(const float* __restrict__ w,
                                                 unsigned short* __restrict__ wT) {
    __shared__ float tile[64][65];
    const int n0 = blockIdx.x * 64;   // 48 blocks
    const int k0 = blockIdx.y * 64;   // 16 blocks
    const int t = threadIdx.x;
    const int tx = t & 63, ty = t >> 6;
    #pragma unroll
    for (int i = 0; i < 16; i++) {
        int r = i * 4 + ty;
        tile[r][tx] = w[(size_t)(k0 + r) * NQKV + n0 + tx];
    }
    __syncthreads();
    #pragma unroll
    for (int i = 0; i < 16; i++) {
        int r = i * 4 + ty;
        wT[(size_t)(n0 + r) * D_ + k0 + tx] = f2bf(tile[tx][r]);
    }
}

// ---------------- Kernel 3: fused QKV GEMM (bf16 MFMA) + activations ----------
// (proven 229-us structure, untouched)
#define CT_STRIDE 136
__global__ __launch_bounds__(256, 3) void qkv_gemm(const unsigned short* __restrict__ xn,
                                                   const unsigned short* __restrict__ wT,
                                                   const int* __restrict__ mask,
                                                   unsigned short* __restrict__ qws,
                                                   unsigned short* __restrict__ kT,
                                                   unsigned short* __restrict__ vT) {
    __shared__ unsigned short ShB[128 * CT_STRIDE];   // 34816 B; mainloop uses 32 KB
    const int t = threadIdx.x;
    const int w = t >> 6, l = t & 63;
    const int quad = l >> 4, ln16 = l & 15;
    const int m0 = blockIdx.y * 128;
    const int n0 = blockIdx.x * 128;
    const int wm = (w >> 1) * 64, wn = (w & 1) * 64;

    f32x4 acc[4][4] = {};

    const unsigned short* aG = xn + (size_t)(m0 + w * 16 + (l >> 2)) * D_ + (l & 3) * 8;
    const unsigned short* bG = wT + (size_t)(n0 + w * 16 + (l >> 2)) * D_ + (l & 3) * 8;
    char* SB = (char*)ShB;
    // staging layout: A stage s at SB + s*8192 (two 4KB halves); B at +16384.

    for (int k0 = 0; k0 < 1024; k0 += 64) {
        #pragma unroll
        for (int s = 0; s < 2; s++) {
            gl_lds16(aG + k0 + s * 32,            SB + s * 8192 + w * 1024);
            gl_lds16(aG + 64 * D_ + k0 + s * 32,  SB + s * 8192 + 4096 + w * 1024);
            gl_lds16(bG + k0 + s * 32,            SB + 16384 + s * 8192 + w * 1024);
            gl_lds16(bG + 64 * D_ + k0 + s * 32,  SB + 16384 + s * 8192 + 4096 + w * 1024);
        }
        __syncthreads();   // drains vmcnt for global_load_lds
        #pragma unroll
        for (int s = 0; s < 2; s++) {
            const char* A0 = SB + s * 8192;
            const char* B0 = SB + 16384 + s * 8192;
            bf16x8 af[4], bfr[4];
            #pragma unroll
            for (int mi = 0; mi < 4; mi++)
                af[mi] = *(const bf16x8*)(A0 + (wm + mi * 16 + ln16) * 64 + quad * 16);
            #pragma unroll
            for (int ni = 0; ni < 4; ni++)
                bfr[ni] = *(const bf16x8*)(B0 + (wn + ni * 16 + ln16) * 64 + quad * 16);
            #pragma unroll
            for (int mi = 0; mi < 4; mi++)
                #pragma unroll
                for (int ni = 0; ni < 4; ni++)
                    acc[mi][ni] = __builtin_amdgcn_mfma_f32_16x16x32_bf16(af[mi], bfr[ni],
                                                                          acc[mi][ni], 0, 0, 0);
        }
        __syncthreads();
    }

    // epilogue: region 0=q (sigmoid, token-major), 1=k (tanh+mask, transposed),
    //           2=v (identity, transposed)
    const int region = n0 >> 10;
    const int cbase = n0 & 1023;
    if (region == 0) {
        #pragma unroll
        for (int mi = 0; mi < 4; mi++) {
            #pragma unroll
            for (int r = 0; r < 4; r++) {
                int gm = m0 + wm + mi * 16 + quad * 4 + r;   // C/D row = quad*4+reg
                #pragma unroll
                for (int ni = 0; ni < 4; ni++) {
                    int cc = cbase + wn + ni * 16 + ln16;    // C/D col = lane&15
                    qws[(size_t)gm * D_ + cc] = f2bf(fast_sigmoid(acc[mi][ni][r]));
                }
            }
        }
    } else {
        // phase 1: store tile into LDS transposed [feat][tok], packed 4 toks/write
        #pragma unroll
        for (int mi = 0; mi < 4; mi++) {
            int tok0 = wm + mi * 16 + quad * 4;
            int mk0 = 0, mk1 = 0, mk2 = 0, mk3 = 0;
            if (region == 1) {
                mk0 = mask[m0 + tok0];
                mk1 = mask[m0 + tok0 + 1];
                mk2 = mask[m0 + tok0 + 2];
                mk3 = mask[m0 + tok0 + 3];
            }
            #pragma unroll
            for (int ni = 0; ni < 4; ni++) {
                int fl = wn + ni * 16 + ln16;
                float v0 = acc[mi][ni][0], v1 = acc[mi][ni][1];
                float v2 = acc[mi][ni][2], v3 = acc[mi][ni][3];
                if (region == 1) {
                    v0 = mk0 ? 0.0f : fast_tanh(v0);
                    v1 = mk1 ? 0.0f : fast_tanh(v1);
                    v2 = mk2 ? 0.0f : fast_tanh(v2);
                    v3 = mk3 ? 0.0f : fast_tanh(v3);
                }
                ushort4 pk;
                pk.x = f2bf(v0); pk.y = f2bf(v1); pk.z = f2bf(v2); pk.w = f2bf(v3);
                *(ushort4*)&ShB[fl * CT_STRIDE + tok0] = pk;   // 8B-aligned ds_write_b64
            }
        }
        __syncthreads();
        // phase 2: coalesced transposed global write (256B per feature row)
        unsigned short* dstT = (region == 1) ? kT : vT;
        const int h = cbase >> 7;          // block covers exactly one head
        const int b = m0 >> 13;
        const int ntok0 = m0 & 8191;
        #pragma unroll
        for (int p = 0; p < 8; p++) {
            int fl = p * 16 + (t >> 4);
            int tok = (t & 15) * 8;
            uint4 u = *(const uint4*)&ShB[fl * CT_STRIDE + tok];   // 16B-aligned b128
            *(uint4*)(dstT + ((size_t)(b * 8 + h) * 128 + fl) * 8192 + ntok0 + tok) = u;
        }
    }
}

// ---------------- Kernel 4: kv partials, LDS-free direct-fragment streaming ---
// kT/vT are feature-major: an MFMA fragment is 16 contiguous bytes per lane at
// row*8192 + k (full 128-B line per row per BK=64 iteration -> no over-fetch).
// No LDS, no barriers: compiler software-pipelines the unrolled loop freely.
// grid (16 chunks, 32 bh) = 512 blocks; partials 32 MB into dead xn region.
__global__ __launch_bounds__(256) void kv_mfma(const unsigned short* __restrict__ kT,
                                               const unsigned short* __restrict__ vT,
                                               float* __restrict__ kvp) {
    const int t = threadIdx.x;
    const int w = t >> 6, l = t & 63;
    const int quad = l >> 4, ln16 = l & 15;
    const int bh = blockIdx.y;
    const int kc0 = blockIdx.x * 512;
    const int wm = (w >> 1) * 64, wn = (w & 1) * 64;

    f32x4 acc[4][4] = {};

    const size_t base = (size_t)bh * 128 * 8192;
    const unsigned short* aBase = kT + base + kc0 + quad * 8;
    const unsigned short* bBase = vT + base + kc0 + quad * 8;

    #pragma unroll 2
    for (int kk = 0; kk < 512; kk += 64) {
        bf16x8 af[4][2], bfr[4][2];
        #pragma unroll
        for (int mi = 0; mi < 4; mi++) {
            const unsigned short* p = aBase + (size_t)(wm + mi * 16 + ln16) * 8192 + kk;
            af[mi][0] = *(const bf16x8*)(p);
            af[mi][1] = *(const bf16x8*)(p + 32);
        }
        #pragma unroll
        for (int ni = 0; ni < 4; ni++) {
            const unsigned short* p = bBase + (size_t)(wn + ni * 16 + ln16) * 8192 + kk;
            bfr[ni][0] = *(const bf16x8*)(p);
            bfr[ni][1] = *(const bf16x8*)(p + 32);
        }
        #pragma unroll
        for (int mi = 0; mi < 4; mi++)
            #pragma unroll
            for (int ni = 0; ni < 4; ni++) {
                acc[mi][ni] = __builtin_amdgcn_mfma_f32_16x16x32_bf16(af[mi][0], bfr[ni][0],
                                                                      acc[mi][ni], 0, 0, 0);
                acc[mi][ni] = __builtin_amdgcn_mfma_f32_16x16x32_bf16(af[mi][1], bfr[ni][1],
                                                                      acc[mi][ni], 0, 0, 0);
            }
    }

    float* dst = kvp + ((size_t)blockIdx.x * 32 + bh) * (HD_ * HD_);
    #pragma unroll
    for (int mi = 0; mi < 4; mi++) {
        #pragma unroll
        for (int r = 0; r < 4; r++) {
            int d = wm + mi * 16 + quad * 4 + r;
            #pragma unroll
            for (int ni = 0; ni < 4; ni++) {
                int e = wn + ni * 16 + ln16;
                dst[d * HD_ + e] = acc[mi][ni][r];
            }
        }
    }
}

// ---------------- Kernel 4b: reduce 16 partials + transpose + cast -> kvTb bf16 [bh][e][d]
__global__ __launch_bounds__(256) void kvcvt(const float* __restrict__ kvp,
                                             unsigned short* __restrict__ kvTb) {
    __shared__ float tile[32][132];
    const int bh = blockIdx.x;
    const int c = blockIdx.y;     // d-chunk of 32
    const int t = threadIdx.x;
    {
        int r = t >> 3, cc = (t & 7) * 16;
        f32x4 s[4] = {};
        for (int p = 0; p < 16; p++) {
            const float* src = kvp + ((size_t)p * 32 + bh) * (HD_ * HD_)
                               + (size_t)(c * 32 + r) * 128 + cc;
            #pragma unroll
            for (int q4 = 0; q4 < 4; q4++)
                s[q4] += *(const f32x4*)(src + q4 * 4);
        }
        #pragma unroll
        for (int q4 = 0; q4 < 4; q4++)
            *(f32x4*)&tile[r][cc + q4 * 4] = s[q4];
    }
    __syncthreads();
    {
        int e = t >> 1, dh = t & 1;
        ushort4 o[4];
        #pragma unroll
        for (int q4 = 0; q4 < 4; q4++) {
            o[q4].x = f2bf(tile[dh * 16 + q4 * 4 + 0][e]);
            o[q4].y = f2bf(tile[dh * 16 + q4 * 4 + 1][e]);
            o[q4].z = f2bf(tile[dh * 16 + q4 * 4 + 2][e]);
            o[q4].w = f2bf(tile[dh * 16 + q4 * 4 + 3][e]);
        }
        unsigned short* dst = kvTb + (size_t)bh * 16384 + e * 128 + c * 32 + dh * 16;
        #pragma unroll
        for (int q4 = 0; q4 < 4; q4++)
            ((ushort4*)dst)[q4] = o[q4];
    }
}

// ---------------- Kernel 5: out = q . kv, LDS-free direct-fragment ------------
// A (q, token-major) fragment = 16 contiguous bytes per lane along feat;
// B (kvTb, 1 MB, L2-hot) fragment likewise. No LDS, no barriers; K=128 fully
// unrolled -> compiler pipelines loads across the whole kernel.
__global__ __launch_bounds__(256) void out_mfma(const unsigned short* __restrict__ qws,
                                                const unsigned short* __restrict__ kvTb,
                                                float* __restrict__ out) {
    const int t = threadIdx.x;
    const int w = t >> 6, l = t & 63;
    const int quad = l >> 4, ln16 = l & 15;
    const int m0 = blockIdx.x * 128;
    const int h = blockIdx.y;
    const int b = m0 >> 13;
    const int bh = b * 8 + h;
    const int wm = (w >> 1) * 64, wn = (w & 1) * 64;

    f32x4 acc[4][4] = {};

    const unsigned short* aBase = qws + (size_t)m0 * D_ + h * HD_ + quad * 8;
    const unsigned short* bBase = kvTb + (size_t)bh * 16384 + quad * 8;

    #pragma unroll
    for (int ks = 0; ks < 4; ks++) {
        bf16x8 af[4], bfr[4];
        #pragma unroll
        for (int mi = 0; mi < 4; mi++)
            af[mi] = *(const bf16x8*)(aBase + (size_t)(wm + mi * 16 + ln16) * D_ + ks * 32);
        #pragma unroll
        for (int ni = 0; ni < 4; ni++)
            bfr[ni] = *(const bf16x8*)(bBase + (wn + ni * 16 + ln16) * 128 + ks * 32);
        #pragma unroll
        for (int mi = 0; mi < 4; mi++)
            #pragma unroll
            for (int ni = 0; ni < 4; ni++)
                acc[mi][ni] = __builtin_amdgcn_mfma_f32_16x16x32_bf16(af[mi], bfr[ni],
                                                                      acc[mi][ni], 0, 0, 0);
    }

    #pragma unroll
    for (int mi = 0; mi < 4; mi++) {
        #pragma unroll
        for (int r = 0; r < 4; r++) {
            int gm = m0 + wm + mi * 16 + quad * 4 + r;
            #pragma unroll
            for (int ni = 0; ni < 4; ni++) {
                int e = wn + ni * 16 + ln16;
                out[(size_t)gm * D_ + h * HD_ + e] = acc[mi][ni][r];
            }
        }
    }
}

// ---------------- launch ----------------
extern "C" void kernel_launch(void* const* d_in, const int* in_sizes, int n_in,
                              void* d_out, int out_size, void* d_ws, size_t ws_size,
                              hipStream_t stream) {
    const float* x     = (const float*)d_in[0];
    const int*   mask  = (const int*)d_in[1];
    const float* w     = (const float*)d_in[2];
    const float* gamma = (const float*)d_in[3];
    const float* beta  = (const float*)d_in[4];
    float* out = (float*)d_out;
    char* ws = (char*)d_ws;

    // workspace layout (~276 MB)
    unsigned short* xn  = (unsigned short*)(ws + 0);              // 64 MB (dead after qkv)
    unsigned short* wT  = (unsigned short*)(ws + 67108864ull);    // 6 MB
    unsigned short* qws = (unsigned short*)(ws + 73400320ull);    // 64 MB
    unsigned short* kT  = (unsigned short*)(ws + 140509184ull);   // 64 MB [bh][128][8192]
    unsigned short* vT  = (unsigned short*)(ws + 207618048ull);   // 64 MB [bh][128][8192]
    unsigned short* kvTb = (unsigned short*)(ws + 274726912ull);  // 1 MB bf16 [bh][e][d]
    // kv partials reuse the (dead-by-then) xn region: 16*32*128*128*4 = 32 MB
    float* kvp = (float*)(ws + 0);

    hipLaunchKernelGGL(ln_kernel, dim3(M_TOT / 4), dim3(256), 0, stream, x, gamma, beta, xn);
    hipLaunchKernelGGL(wt_kernel, dim3(48, 16), dim3(256), 0, stream, w, wT);
    hipLaunchKernelGGL(qkv_gemm, dim3(NQKV / 128, M_TOT / 128), dim3(256), 0, stream,
                       xn, wT, mask, qws, kT, vT);
    hipLaunchKernelGGL(kv_mfma, dim3(16, 32), dim3(256), 0, stream, kT, vT, kvp);
    hipLaunchKernelGGL(kvcvt, dim3(32, 4), dim3(256), 0, stream, kvp, kvTb);
    hipLaunchKernelGGL(out_mfma, dim3(M_TOT / 128, 8), dim3(256), 0, stream,
                       qws, kvTb, out);
}

// Round 6
// 518.663 us; speedup vs baseline: 1.0764x; 1.0764x over previous
//
#include <hip/hip_runtime.h>

// Problem constants
#define EPS 1e-5f
#define B_ 4
#define N_ 8192
#define D_ 1024
#define H_ 8
#define HD_ 128
#define M_TOT 32768   // B*N
#define NQKV 3072     // 3*D

typedef __bf16 bf16x8 __attribute__((ext_vector_type(8)));
typedef float f32x4 __attribute__((ext_vector_type(4)));

__device__ __forceinline__ float bf2f(unsigned short u) {
    unsigned int v = ((unsigned int)u) << 16;
    return __uint_as_float(v);
}
__device__ __forceinline__ unsigned short f2bf(float f) {
    unsigned int u = __float_as_uint(f);
    u += 0x7fffu + ((u >> 16) & 1u);   // RNE
    return (unsigned short)(u >> 16);
}

// fast activations: v_exp_f32 + v_rcp_f32 (~1e-6 rel err, saturates correctly)
__device__ __forceinline__ float fast_sigmoid(float v) {
    return __builtin_amdgcn_rcpf(1.0f + __expf(-v));
}
__device__ __forceinline__ float fast_tanh(float v) {
    return 1.0f - 2.0f * __builtin_amdgcn_rcpf(1.0f + __expf(2.0f * v));
}

// async global->LDS, 16B per lane; LDS dest is wave-uniform base + lane*16
__device__ __forceinline__ void gl_lds16(const void* g, void* l) {
    __builtin_amdgcn_global_load_lds(
        (const __attribute__((address_space(1))) unsigned int*)g,
        (__attribute__((address_space(3))) unsigned int*)l, 16, 0, 0);
}

// ---------------- Kernel 1: LayerNorm -> bf16 xn [32768][1024] ----------------
// One wave per row, 16 elems/lane, register-only shfl reduction (r3-best version).
__global__ __launch_bounds__(64) void ln_kernel(const float* __restrict__ x,
                                                const float* __restrict__ gamma,
                                                const float* __restrict__ beta,
                                                unsigned short* __restrict__ xn) {
    const int row = blockIdx.x;
    const int t = threadIdx.x;   // 0..63
    const float* xr = x + (size_t)row * D_;
    float4 xv[4];
    #pragma unroll
    for (int i = 0; i < 4; i++) xv[i] = ((const float4*)xr)[i * 64 + t];
    float s = 0.0f, s2 = 0.0f;
    #pragma unroll
    for (int i = 0; i < 4; i++) {
        s  += xv[i].x + xv[i].y + xv[i].z + xv[i].w;
        s2 += xv[i].x * xv[i].x + xv[i].y * xv[i].y
            + xv[i].z * xv[i].z + xv[i].w * xv[i].w;
    }
    #pragma unroll
    for (int off = 32; off > 0; off >>= 1) {
        s  += __shfl_down(s, off);
        s2 += __shfl_down(s2, off);
    }
    s = __shfl(s, 0);
    s2 = __shfl(s2, 0);
    const float mu = s * (1.0f / D_);
    const float var = s2 * (1.0f / D_) - mu * mu;
    const float rs = rsqrtf(var + EPS);
    unsigned short* xo = xn + (size_t)row * D_;
    #pragma unroll
    for (int i = 0; i < 4; i++) {
        float4 g  = ((const float4*)gamma)[i * 64 + t];
        float4 bt = ((const float4*)beta)[i * 64 + t];
        ushort4 o;
        o.x = f2bf((xv[i].x - mu) * rs * g.x + bt.x);
        o.y = f2bf((xv[i].y - mu) * rs * g.y + bt.y);
        o.z = f2bf((xv[i].z - mu) * rs * g.z + bt.z);
        o.w = f2bf((xv[i].w - mu) * rs * g.w + bt.w);
        ((ushort4*)xo)[i * 64 + t] = o;
    }
}

// ---------------- Kernel 2: transpose+cast w [1024][3072] -> wT bf16 [3072][1024]
__global__ __launch_bounds__(256) void wt_kernel(const float* __restrict__ w,
                                                 unsigned short* __restrict__ wT) {
    __shared__ float tile[64][65];
    const int n0 = blockIdx.x * 64;   // 48 blocks
    const int k0 = blockIdx.y * 64;   // 16 blocks
    const int t = threadIdx.x;
    const int tx = t & 63, ty = t >> 6;
    #pragma unroll
    for (int i = 0; i < 16; i++) {
        int r = i * 4 + ty;
        tile[r][tx] = w[(size_t)(k0 + r) * NQKV + n0 + tx];
    }
    __syncthreads();
    #pragma unroll
    for (int i = 0; i < 16; i++) {
        int r = i * 4 + ty;
        wT[(size_t)(n0 + r) * D_ + k0 + tx] = f2bf(tile[tx][r]);
    }
}

// ---------------- Kernel 3a: K/V GEMM (k,v regions only) + transpose epilogue -
// Proven 229-us qkv structure; n0 offset by 1024 so region in {1,2}.
#define CT_STRIDE 136
__global__ __launch_bounds__(256, 3) void qkv_kv(const unsigned short* __restrict__ xn,
                                                 const unsigned short* __restrict__ wT,
                                                 const int* __restrict__ mask,
                                                 unsigned short* __restrict__ kT,
                                                 unsigned short* __restrict__ vT) {
    __shared__ unsigned short ShB[128 * CT_STRIDE];   // 34816 B; mainloop uses 32 KB
    const int t = threadIdx.x;
    const int w = t >> 6, l = t & 63;
    const int quad = l >> 4, ln16 = l & 15;
    const int m0 = blockIdx.y * 128;
    const int n0 = 1024 + blockIdx.x * 128;   // k/v regions only
    const int wm = (w >> 1) * 64, wn = (w & 1) * 64;

    f32x4 acc[4][4] = {};

    const unsigned short* aG = xn + (size_t)(m0 + w * 16 + (l >> 2)) * D_ + (l & 3) * 8;
    const unsigned short* bG = wT + (size_t)(n0 + w * 16 + (l >> 2)) * D_ + (l & 3) * 8;
    char* SB = (char*)ShB;

    for (int k0 = 0; k0 < 1024; k0 += 64) {
        #pragma unroll
        for (int s = 0; s < 2; s++) {
            gl_lds16(aG + k0 + s * 32,            SB + s * 8192 + w * 1024);
            gl_lds16(aG + 64 * D_ + k0 + s * 32,  SB + s * 8192 + 4096 + w * 1024);
            gl_lds16(bG + k0 + s * 32,            SB + 16384 + s * 8192 + w * 1024);
            gl_lds16(bG + 64 * D_ + k0 + s * 32,  SB + 16384 + s * 8192 + 4096 + w * 1024);
        }
        __syncthreads();
        #pragma unroll
        for (int s = 0; s < 2; s++) {
            const char* A0 = SB + s * 8192;
            const char* B0 = SB + 16384 + s * 8192;
            bf16x8 af[4], bfr[4];
            #pragma unroll
            for (int mi = 0; mi < 4; mi++)
                af[mi] = *(const bf16x8*)(A0 + (wm + mi * 16 + ln16) * 64 + quad * 16);
            #pragma unroll
            for (int ni = 0; ni < 4; ni++)
                bfr[ni] = *(const bf16x8*)(B0 + (wn + ni * 16 + ln16) * 64 + quad * 16);
            #pragma unroll
            for (int mi = 0; mi < 4; mi++)
                #pragma unroll
                for (int ni = 0; ni < 4; ni++)
                    acc[mi][ni] = __builtin_amdgcn_mfma_f32_16x16x32_bf16(af[mi], bfr[ni],
                                                                          acc[mi][ni], 0, 0, 0);
        }
        __syncthreads();
    }

    const int region = n0 >> 10;          // 1=k, 2=v
    const int cbase = n0 & 1023;
    // phase 1: store tile into LDS transposed [feat][tok], packed 4 toks/write
    #pragma unroll
    for (int mi = 0; mi < 4; mi++) {
        int tok0 = wm + mi * 16 + quad * 4;
        int mk0 = 0, mk1 = 0, mk2 = 0, mk3 = 0;
        if (region == 1) {
            mk0 = mask[m0 + tok0];
            mk1 = mask[m0 + tok0 + 1];
            mk2 = mask[m0 + tok0 + 2];
            mk3 = mask[m0 + tok0 + 3];
        }
        #pragma unroll
        for (int ni = 0; ni < 4; ni++) {
            int fl = wn + ni * 16 + ln16;
            float v0 = acc[mi][ni][0], v1 = acc[mi][ni][1];
            float v2 = acc[mi][ni][2], v3 = acc[mi][ni][3];
            if (region == 1) {
                v0 = mk0 ? 0.0f : fast_tanh(v0);
                v1 = mk1 ? 0.0f : fast_tanh(v1);
                v2 = mk2 ? 0.0f : fast_tanh(v2);
                v3 = mk3 ? 0.0f : fast_tanh(v3);
            }
            ushort4 pk;
            pk.x = f2bf(v0); pk.y = f2bf(v1); pk.z = f2bf(v2); pk.w = f2bf(v3);
            *(ushort4*)&ShB[fl * CT_STRIDE + tok0] = pk;   // 8B-aligned ds_write_b64
        }
    }
    __syncthreads();
    // phase 2: coalesced transposed global write (256B per feature row)
    unsigned short* dstT = (region == 1) ? kT : vT;
    const int h = cbase >> 7;          // block covers exactly one head
    const int b = m0 >> 13;
    const int ntok0 = m0 & 8191;
    #pragma unroll
    for (int p = 0; p < 8; p++) {
        int fl = p * 16 + (t >> 4);
        int tok = (t & 15) * 8;
        uint4 u = *(const uint4*)&ShB[fl * CT_STRIDE + tok];   // 16B-aligned b128
        *(uint4*)(dstT + ((size_t)(b * 8 + h) * 128 + fl) * 8192 + ntok0 + tok) = u;
    }
}

// ---------------- Kernel 4: kv partials (r3-best version) ---------------------
// BK=64, XOR-swizzled LDS (granule ^= row&7) for conflict-free b128 fragment
// reads; per-(chunk,bh) partial tiles (no atomics). grid (16 chunks, 32 bh).
__global__ __launch_bounds__(256) void kv_mfma(const unsigned short* __restrict__ kT,
                                               const unsigned short* __restrict__ vT,
                                               float* __restrict__ kvp) {
    __shared__ __align__(16) char smem[32768];   // A 16KB + B 16KB
    char* AsB = smem;
    char* BsB = smem + 16384;
    const int t = threadIdx.x;
    const int w = t >> 6, l = t & 63;
    const int quad = l >> 4, ln16 = l & 15;
    const int bh = blockIdx.y;
    const int kc0 = blockIdx.x * 512;
    const int wm = (w >> 1) * 64, wn = (w & 1) * 64;

    f32x4 acc[4][4] = {};

    const size_t base = (size_t)bh * 128 * 8192;
    const int gsw = (l & 7) ^ (l >> 3);
    const unsigned short* aG = kT + base + (size_t)(w * 8 + (l >> 3)) * 8192 + kc0 + gsw * 8;
    const unsigned short* bG = vT + base + (size_t)(w * 8 + (l >> 3)) * 8192 + kc0 + gsw * 8;
    const int r7 = ln16 & 7;
    const int kb0 = ((quad ^ r7) << 4);
    const int kb1 = (((4 | quad) ^ r7) << 4);

    for (int kk = 0; kk < 512; kk += 64) {
        #pragma unroll
        for (int c = 0; c < 4; c++) {
            gl_lds16(aG + (size_t)(c * 32) * 8192 + kk, AsB + c * 4096 + w * 1024);
            gl_lds16(bG + (size_t)(c * 32) * 8192 + kk, BsB + c * 4096 + w * 1024);
        }
        __syncthreads();
        bf16x8 af[4][2], bfr[4][2];
        #pragma unroll
        for (int mi = 0; mi < 4; mi++) {
            const char* rp = AsB + (wm + mi * 16 + ln16) * 128;
            af[mi][0] = *(const bf16x8*)(rp + kb0);
            af[mi][1] = *(const bf16x8*)(rp + kb1);
        }
        #pragma unroll
        for (int ni = 0; ni < 4; ni++) {
            const char* rp = BsB + (wn + ni * 16 + ln16) * 128;
            bfr[ni][0] = *(const bf16x8*)(rp + kb0);
            bfr[ni][1] = *(const bf16x8*)(rp + kb1);
        }
        #pragma unroll
        for (int mi = 0; mi < 4; mi++)
            #pragma unroll
            for (int ni = 0; ni < 4; ni++) {
                acc[mi][ni] = __builtin_amdgcn_mfma_f32_16x16x32_bf16(af[mi][0], bfr[ni][0],
                                                                      acc[mi][ni], 0, 0, 0);
                acc[mi][ni] = __builtin_amdgcn_mfma_f32_16x16x32_bf16(af[mi][1], bfr[ni][1],
                                                                      acc[mi][ni], 0, 0, 0);
            }
        __syncthreads();
    }

    float* dst = kvp + ((size_t)blockIdx.x * 32 + bh) * (HD_ * HD_);
    #pragma unroll
    for (int mi = 0; mi < 4; mi++) {
        #pragma unroll
        for (int r = 0; r < 4; r++) {
            int d = wm + mi * 16 + quad * 4 + r;
            #pragma unroll
            for (int ni = 0; ni < 4; ni++) {
                int e = wn + ni * 16 + ln16;
                dst[d * HD_ + e] = acc[mi][ni][r];
            }
        }
    }
}

// ---------------- Kernel 4b: reduce 16 partials + transpose + cast -> kvTb ----
__global__ __launch_bounds__(256) void kvcvt(const float* __restrict__ kvp,
                                             unsigned short* __restrict__ kvTb) {
    __shared__ float tile[32][132];
    const int bh = blockIdx.x;
    const int c = blockIdx.y;     // d-chunk of 32
    const int t = threadIdx.x;
    {
        int r = t >> 3, cc = (t & 7) * 16;
        f32x4 s[4] = {};
        for (int p = 0; p < 16; p++) {
            const float* src = kvp + ((size_t)p * 32 + bh) * (HD_ * HD_)
                               + (size_t)(c * 32 + r) * 128 + cc;
            #pragma unroll
            for (int q4 = 0; q4 < 4; q4++)
                s[q4] += *(const f32x4*)(src + q4 * 4);
        }
        #pragma unroll
        for (int q4 = 0; q4 < 4; q4++)
            *(f32x4*)&tile[r][cc + q4 * 4] = s[q4];
    }
    __syncthreads();
    {
        int e = t >> 1, dh = t & 1;
        ushort4 o[4];
        #pragma unroll
        for (int q4 = 0; q4 < 4; q4++) {
            o[q4].x = f2bf(tile[dh * 16 + q4 * 4 + 0][e]);
            o[q4].y = f2bf(tile[dh * 16 + q4 * 4 + 1][e]);
            o[q4].z = f2bf(tile[dh * 16 + q4 * 4 + 2][e]);
            o[q4].w = f2bf(tile[dh * 16 + q4 * 4 + 3][e]);
        }
        unsigned short* dst = kvTb + (size_t)bh * 16384 + e * 128 + c * 32 + dh * 16;
        #pragma unroll
        for (int q4 = 0; q4 < 4; q4++)
            ((ushort4*)dst)[q4] = o[q4];
    }
}

// ---------------- Kernel 3b: Q GEMM + fused out = sigmoid(q) . kv -------------
// Same proven GEMM main loop (q columns only). Epilogue: sigmoid(acc) -> bf16
// into ShB as [tok][d] (stride 136 shorts, 34816 B -> occupancy unchanged),
// barrier, then 64 MFMAs against L2-hot kvTb[bh] and direct fp32 out write.
// Deletes the 64 MB qws write + 64 MB read + the separate out_mfma dispatch.
__global__ __launch_bounds__(256, 3) void qkv_q_out(const unsigned short* __restrict__ xn,
                                                    const unsigned short* __restrict__ wT,
                                                    const unsigned short* __restrict__ kvTb,
                                                    float* __restrict__ out) {
    __shared__ unsigned short ShB[128 * CT_STRIDE];   // 34816 B
    const int t = threadIdx.x;
    const int w = t >> 6, l = t & 63;
    const int quad = l >> 4, ln16 = l & 15;
    const int m0 = blockIdx.x * 128;
    const int h = blockIdx.y;
    const int n0 = h * 128;               // q region columns
    const int b = m0 >> 13;
    const int bh = b * 8 + h;
    const int wm = (w >> 1) * 64, wn = (w & 1) * 64;

    f32x4 acc[4][4] = {};

    const unsigned short* aG = xn + (size_t)(m0 + w * 16 + (l >> 2)) * D_ + (l & 3) * 8;
    const unsigned short* bG = wT + (size_t)(n0 + w * 16 + (l >> 2)) * D_ + (l & 3) * 8;
    char* SB = (char*)ShB;

    for (int k0 = 0; k0 < 1024; k0 += 64) {
        #pragma unroll
        for (int s = 0; s < 2; s++) {
            gl_lds16(aG + k0 + s * 32,            SB + s * 8192 + w * 1024);
            gl_lds16(aG + 64 * D_ + k0 + s * 32,  SB + s * 8192 + 4096 + w * 1024);
            gl_lds16(bG + k0 + s * 32,            SB + 16384 + s * 8192 + w * 1024);
            gl_lds16(bG + 64 * D_ + k0 + s * 32,  SB + 16384 + s * 8192 + 4096 + w * 1024);
        }
        __syncthreads();
        #pragma unroll
        for (int s = 0; s < 2; s++) {
            const char* A0 = SB + s * 8192;
            const char* B0 = SB + 16384 + s * 8192;
            bf16x8 af[4], bfr[4];
            #pragma unroll
            for (int mi = 0; mi < 4; mi++)
                af[mi] = *(const bf16x8*)(A0 + (wm + mi * 16 + ln16) * 64 + quad * 16);
            #pragma unroll
            for (int ni = 0; ni < 4; ni++)
                bfr[ni] = *(const bf16x8*)(B0 + (wn + ni * 16 + ln16) * 64 + quad * 16);
            #pragma unroll
            for (int mi = 0; mi < 4; mi++)
                #pragma unroll
                for (int ni = 0; ni < 4; ni++)
                    acc[mi][ni] = __builtin_amdgcn_mfma_f32_16x16x32_bf16(af[mi], bfr[ni],
                                                                          acc[mi][ni], 0, 0, 0);
        }
        __syncthreads();
    }

    // epilogue phase 1: sigmoid -> bf16 -> ShB[tok][d], row stride 136 shorts
    #pragma unroll
    for (int mi = 0; mi < 4; mi++) {
        int tok0 = wm + mi * 16 + quad * 4;
        #pragma unroll
        for (int ni = 0; ni < 4; ni++) {
            int d = wn + ni * 16 + ln16;
            #pragma unroll
            for (int r = 0; r < 4; r++)
                ShB[(tok0 + r) * CT_STRIDE + d] = f2bf(fast_sigmoid(acc[mi][ni][r]));
        }
    }
    __syncthreads();

    // epilogue phase 2: out-tile = Q_lds . kvTb[bh]^T  (K = 128, 4 ks steps)
    const char* bB = (const char*)kvTb + (size_t)bh * 32768;
    f32x4 acc2[4][4] = {};
    #pragma unroll
    for (int ks = 0; ks < 4; ks++) {
        bf16x8 qa[4], kb[4];
        #pragma unroll
        for (int ni = 0; ni < 4; ni++)
            kb[ni] = *(const bf16x8*)(bB + (wn + ni * 16 + ln16) * 256 + ks * 64 + quad * 16);
        #pragma unroll
        for (int mi = 0; mi < 4; mi++)
            qa[mi] = *(const bf16x8*)((const char*)ShB + (wm + mi * 16 + ln16) * (CT_STRIDE * 2)
                                      + ks * 64 + quad * 16);
        #pragma unroll
        for (int mi = 0; mi < 4; mi++)
            #pragma unroll
            for (int ni = 0; ni < 4; ni++)
                acc2[mi][ni] = __builtin_amdgcn_mfma_f32_16x16x32_bf16(qa[mi], kb[ni],
                                                                       acc2[mi][ni], 0, 0, 0);
    }

    #pragma unroll
    for (int mi = 0; mi < 4; mi++) {
        #pragma unroll
        for (int r = 0; r < 4; r++) {
            int gm = m0 + wm + mi * 16 + quad * 4 + r;
            #pragma unroll
            for (int ni = 0; ni < 4; ni++) {
                int e = wn + ni * 16 + ln16;
                out[(size_t)gm * D_ + h * HD_ + e] = acc2[mi][ni][r];
            }
        }
    }
}

// ---------------- launch ----------------
extern "C" void kernel_launch(void* const* d_in, const int* in_sizes, int n_in,
                              void* d_out, int out_size, void* d_ws, size_t ws_size,
                              hipStream_t stream) {
    const float* x     = (const float*)d_in[0];
    const int*   mask  = (const int*)d_in[1];
    const float* w     = (const float*)d_in[2];
    const float* gamma = (const float*)d_in[3];
    const float* beta  = (const float*)d_in[4];
    float* out = (float*)d_out;
    char* ws = (char*)d_ws;

    // workspace layout (~276 MB)
    unsigned short* xn  = (unsigned short*)(ws + 0);              // 64 MB (live until qkv_q_out)
    unsigned short* wT  = (unsigned short*)(ws + 67108864ull);    // 6 MB
    float* kvp          = (float*)(ws + 73400320ull);             // 32 MB (old qws region)
    unsigned short* kT  = (unsigned short*)(ws + 140509184ull);   // 64 MB [bh][128][8192]
    unsigned short* vT  = (unsigned short*)(ws + 207618048ull);   // 64 MB [bh][128][8192]
    unsigned short* kvTb = (unsigned short*)(ws + 274726912ull);  // 1 MB bf16 [bh][e][d]

    hipLaunchKernelGGL(ln_kernel, dim3(M_TOT), dim3(64), 0, stream, x, gamma, beta, xn);
    hipLaunchKernelGGL(wt_kernel, dim3(48, 16), dim3(256), 0, stream, w, wT);
    hipLaunchKernelGGL(qkv_kv, dim3(16, M_TOT / 128), dim3(256), 0, stream,
                       xn, wT, mask, kT, vT);
    hipLaunchKernelGGL(kv_mfma, dim3(16, 32), dim3(256), 0, stream, kT, vT, kvp);
    hipLaunchKernelGGL(kvcvt, dim3(32, 4), dim3(256), 0, stream, kvp, kvTb);
    hipLaunchKernelGGL(qkv_q_out, dim3(M_TOT / 128, 8), dim3(256), 0, stream,
                       xn, wT, kvTb, out);
}

// Round 7
// 515.574 us; speedup vs baseline: 1.0828x; 1.0060x over previous
//
#include <hip/hip_runtime.h>

// Problem constants
#define EPS 1e-5f
#define B_ 4
#define N_ 8192
#define D_ 1024
#define H_ 8
#define HD_ 128
#define M_TOT 32768   // B*N
#define NQKV 3072     // 3*D

typedef __bf16 bf16x8 __attribute__((ext_vector_type(8)));
typedef float f32x4 __attribute__((ext_vector_type(4)));

__device__ __forceinline__ float bf2f(unsigned short u) {
    unsigned int v = ((unsigned int)u) << 16;
    return __uint_as_float(v);
}
__device__ __forceinline__ unsigned short f2bf(float f) {
    unsigned int u = __float_as_uint(f);
    u += 0x7fffu + ((u >> 16) & 1u);   // RNE
    return (unsigned short)(u >> 16);
}

// fast activations: v_exp_f32 + v_rcp_f32 (~1e-6 rel err, saturates correctly)
__device__ __forceinline__ float fast_sigmoid(float v) {
    return __builtin_amdgcn_rcpf(1.0f + __expf(-v));
}
__device__ __forceinline__ float fast_tanh(float v) {
    return 1.0f - 2.0f * __builtin_amdgcn_rcpf(1.0f + __expf(2.0f * v));
}

// async global->LDS, 16B per lane; LDS dest is wave-uniform base + lane*16
__device__ __forceinline__ void gl_lds16(const void* g, void* l) {
    __builtin_amdgcn_global_load_lds(
        (const __attribute__((address_space(1))) unsigned int*)g,
        (__attribute__((address_space(3))) unsigned int*)l, 16, 0, 0);
}

// ---------------- Kernel 1: LayerNorm -> bf16 xn [32768][1024] ----------------
// One wave per row, 16 elems/lane, register-only shfl reduction.
__global__ __launch_bounds__(64) void ln_kernel(const float* __restrict__ x,
                                                const float* __restrict__ gamma,
                                                const float* __restrict__ beta,
                                                unsigned short* __restrict__ xn) {
    const int row = blockIdx.x;
    const int t = threadIdx.x;   // 0..63
    const float* xr = x + (size_t)row * D_;
    float4 xv[4];
    #pragma unroll
    for (int i = 0; i < 4; i++) xv[i] = ((const float4*)xr)[i * 64 + t];
    float s = 0.0f, s2 = 0.0f;
    #pragma unroll
    for (int i = 0; i < 4; i++) {
        s  += xv[i].x + xv[i].y + xv[i].z + xv[i].w;
        s2 += xv[i].x * xv[i].x + xv[i].y * xv[i].y
            + xv[i].z * xv[i].z + xv[i].w * xv[i].w;
    }
    #pragma unroll
    for (int off = 32; off > 0; off >>= 1) {
        s  += __shfl_down(s, off);
        s2 += __shfl_down(s2, off);
    }
    s = __shfl(s, 0);
    s2 = __shfl(s2, 0);
    const float mu = s * (1.0f / D_);
    const float var = s2 * (1.0f / D_) - mu * mu;
    const float rs = rsqrtf(var + EPS);
    unsigned short* xo = xn + (size_t)row * D_;
    #pragma unroll
    for (int i = 0; i < 4; i++) {
        float4 g  = ((const float4*)gamma)[i * 64 + t];
        float4 bt = ((const float4*)beta)[i * 64 + t];
        ushort4 o;
        o.x = f2bf((xv[i].x - mu) * rs * g.x + bt.x);
        o.y = f2bf((xv[i].y - mu) * rs * g.y + bt.y);
        o.z = f2bf((xv[i].z - mu) * rs * g.z + bt.z);
        o.w = f2bf((xv[i].w - mu) * rs * g.w + bt.w);
        ((ushort4*)xo)[i * 64 + t] = o;
    }
}

// ---------------- Kernel 2: transpose+cast w [1024][3072] -> wT bf16 [3072][1024]
__global__ __launch_bounds__(256) void wt_kernel(const float* __restrict__ w,
                                                 unsigned short* __restrict__ wT) {
    __shared__ float tile[64][65];
    const int n0 = blockIdx.x * 64;   // 48 blocks
    const int k0 = blockIdx.y * 64;   // 16 blocks
    const int t = threadIdx.x;
    const int tx = t & 63, ty = t >> 6;
    #pragma unroll
    for (int i = 0; i < 16; i++) {
        int r = i * 4 + ty;
        tile[r][tx] = w[(size_t)(k0 + r) * NQKV + n0 + tx];
    }
    __syncthreads();
    #pragma unroll
    for (int i = 0; i < 16; i++) {
        int r = i * 4 + ty;
        wT[(size_t)(n0 + r) * D_ + k0 + tx] = f2bf(tile[tx][r]);
    }
}

// ---------------- Kernel 3a: K/V GEMM (k,v regions only) + transpose epilogue -
// Proven structure; n0 offset by 1024 so region in {1,2}. (unchanged from r6)
#define CT_STRIDE 136
__global__ __launch_bounds__(256, 3) void qkv_kv(const unsigned short* __restrict__ xn,
                                                 const unsigned short* __restrict__ wT,
                                                 const int* __restrict__ mask,
                                                 unsigned short* __restrict__ kT,
                                                 unsigned short* __restrict__ vT) {
    __shared__ unsigned short ShB[128 * CT_STRIDE];   // 34816 B; mainloop uses 32 KB
    const int t = threadIdx.x;
    const int w = t >> 6, l = t & 63;
    const int quad = l >> 4, ln16 = l & 15;
    const int m0 = blockIdx.y * 128;
    const int n0 = 1024 + blockIdx.x * 128;   // k/v regions only
    const int wm = (w >> 1) * 64, wn = (w & 1) * 64;

    f32x4 acc[4][4] = {};

    const unsigned short* aG = xn + (size_t)(m0 + w * 16 + (l >> 2)) * D_ + (l & 3) * 8;
    const unsigned short* bG = wT + (size_t)(n0 + w * 16 + (l >> 2)) * D_ + (l & 3) * 8;
    char* SB = (char*)ShB;

    for (int k0 = 0; k0 < 1024; k0 += 64) {
        #pragma unroll
        for (int s = 0; s < 2; s++) {
            gl_lds16(aG + k0 + s * 32,            SB + s * 8192 + w * 1024);
            gl_lds16(aG + 64 * D_ + k0 + s * 32,  SB + s * 8192 + 4096 + w * 1024);
            gl_lds16(bG + k0 + s * 32,            SB + 16384 + s * 8192 + w * 1024);
            gl_lds16(bG + 64 * D_ + k0 + s * 32,  SB + 16384 + s * 8192 + 4096 + w * 1024);
        }
        __syncthreads();
        #pragma unroll
        for (int s = 0; s < 2; s++) {
            const char* A0 = SB + s * 8192;
            const char* B0 = SB + 16384 + s * 8192;
            bf16x8 af[4], bfr[4];
            #pragma unroll
            for (int mi = 0; mi < 4; mi++)
                af[mi] = *(const bf16x8*)(A0 + (wm + mi * 16 + ln16) * 64 + quad * 16);
            #pragma unroll
            for (int ni = 0; ni < 4; ni++)
                bfr[ni] = *(const bf16x8*)(B0 + (wn + ni * 16 + ln16) * 64 + quad * 16);
            #pragma unroll
            for (int mi = 0; mi < 4; mi++)
                #pragma unroll
                for (int ni = 0; ni < 4; ni++)
                    acc[mi][ni] = __builtin_amdgcn_mfma_f32_16x16x32_bf16(af[mi], bfr[ni],
                                                                          acc[mi][ni], 0, 0, 0);
        }
        __syncthreads();
    }

    const int region = n0 >> 10;          // 1=k, 2=v
    const int cbase = n0 & 1023;
    // phase 1: store tile into LDS transposed [feat][tok], packed 4 toks/write
    #pragma unroll
    for (int mi = 0; mi < 4; mi++) {
        int tok0 = wm + mi * 16 + quad * 4;
        int mk0 = 0, mk1 = 0, mk2 = 0, mk3 = 0;
        if (region == 1) {
            mk0 = mask[m0 + tok0];
            mk1 = mask[m0 + tok0 + 1];
            mk2 = mask[m0 + tok0 + 2];
            mk3 = mask[m0 + tok0 + 3];
        }
        #pragma unroll
        for (int ni = 0; ni < 4; ni++) {
            int fl = wn + ni * 16 + ln16;
            float v0 = acc[mi][ni][0], v1 = acc[mi][ni][1];
            float v2 = acc[mi][ni][2], v3 = acc[mi][ni][3];
            if (region == 1) {
                v0 = mk0 ? 0.0f : fast_tanh(v0);
                v1 = mk1 ? 0.0f : fast_tanh(v1);
                v2 = mk2 ? 0.0f : fast_tanh(v2);
                v3 = mk3 ? 0.0f : fast_tanh(v3);
            }
            ushort4 pk;
            pk.x = f2bf(v0); pk.y = f2bf(v1); pk.z = f2bf(v2); pk.w = f2bf(v3);
            *(ushort4*)&ShB[fl * CT_STRIDE + tok0] = pk;   // 8B-aligned ds_write_b64
        }
    }
    __syncthreads();
    // phase 2: coalesced transposed global write (256B per feature row)
    unsigned short* dstT = (region == 1) ? kT : vT;
    const int h = cbase >> 7;          // block covers exactly one head
    const int b = m0 >> 13;
    const int ntok0 = m0 & 8191;
    #pragma unroll
    for (int p = 0; p < 8; p++) {
        int fl = p * 16 + (t >> 4);
        int tok = (t & 15) * 8;
        uint4 u = *(const uint4*)&ShB[fl * CT_STRIDE + tok];   // 16B-aligned b128
        *(uint4*)(dstT + ((size_t)(b * 8 + h) * 128 + fl) * 8192 + ntok0 + tok) = u;
    }
}

// ---------------- Kernel 4: kv partials (unchanged) ---------------------------
__global__ __launch_bounds__(256) void kv_mfma(const unsigned short* __restrict__ kT,
                                               const unsigned short* __restrict__ vT,
                                               float* __restrict__ kvp) {
    __shared__ __align__(16) char smem[32768];   // A 16KB + B 16KB
    char* AsB = smem;
    char* BsB = smem + 16384;
    const int t = threadIdx.x;
    const int w = t >> 6, l = t & 63;
    const int quad = l >> 4, ln16 = l & 15;
    const int bh = blockIdx.y;
    const int kc0 = blockIdx.x * 512;
    const int wm = (w >> 1) * 64, wn = (w & 1) * 64;

    f32x4 acc[4][4] = {};

    const size_t base = (size_t)bh * 128 * 8192;
    const int gsw = (l & 7) ^ (l >> 3);
    const unsigned short* aG = kT + base + (size_t)(w * 8 + (l >> 3)) * 8192 + kc0 + gsw * 8;
    const unsigned short* bG = vT + base + (size_t)(w * 8 + (l >> 3)) * 8192 + kc0 + gsw * 8;
    const int r7 = ln16 & 7;
    const int kb0 = ((quad ^ r7) << 4);
    const int kb1 = (((4 | quad) ^ r7) << 4);

    for (int kk = 0; kk < 512; kk += 64) {
        #pragma unroll
        for (int c = 0; c < 4; c++) {
            gl_lds16(aG + (size_t)(c * 32) * 8192 + kk, AsB + c * 4096 + w * 1024);
            gl_lds16(bG + (size_t)(c * 32) * 8192 + kk, BsB + c * 4096 + w * 1024);
        }
        __syncthreads();
        bf16x8 af[4][2], bfr[4][2];
        #pragma unroll
        for (int mi = 0; mi < 4; mi++) {
            const char* rp = AsB + (wm + mi * 16 + ln16) * 128;
            af[mi][0] = *(const bf16x8*)(rp + kb0);
            af[mi][1] = *(const bf16x8*)(rp + kb1);
        }
        #pragma unroll
        for (int ni = 0; ni < 4; ni++) {
            const char* rp = BsB + (wn + ni * 16 + ln16) * 128;
            bfr[ni][0] = *(const bf16x8*)(rp + kb0);
            bfr[ni][1] = *(const bf16x8*)(rp + kb1);
        }
        #pragma unroll
        for (int mi = 0; mi < 4; mi++)
            #pragma unroll
            for (int ni = 0; ni < 4; ni++) {
                acc[mi][ni] = __builtin_amdgcn_mfma_f32_16x16x32_bf16(af[mi][0], bfr[ni][0],
                                                                      acc[mi][ni], 0, 0, 0);
                acc[mi][ni] = __builtin_amdgcn_mfma_f32_16x16x32_bf16(af[mi][1], bfr[ni][1],
                                                                      acc[mi][ni], 0, 0, 0);
            }
        __syncthreads();
    }

    float* dst = kvp + ((size_t)blockIdx.x * 32 + bh) * (HD_ * HD_);
    #pragma unroll
    for (int mi = 0; mi < 4; mi++) {
        #pragma unroll
        for (int r = 0; r < 4; r++) {
            int d = wm + mi * 16 + quad * 4 + r;
            #pragma unroll
            for (int ni = 0; ni < 4; ni++) {
                int e = wn + ni * 16 + ln16;
                dst[d * HD_ + e] = acc[mi][ni][r];
            }
        }
    }
}

// ---------------- Kernel 4b: reduce 16 partials + transpose + cast -> kvTb ----
__global__ __launch_bounds__(256) void kvcvt(const float* __restrict__ kvp,
                                             unsigned short* __restrict__ kvTb) {
    __shared__ float tile[32][132];
    const int bh = blockIdx.x;
    const int c = blockIdx.y;     // d-chunk of 32
    const int t = threadIdx.x;
    {
        int r = t >> 3, cc = (t & 7) * 16;
        f32x4 s[4] = {};
        for (int p = 0; p < 16; p++) {
            const float* src = kvp + ((size_t)p * 32 + bh) * (HD_ * HD_)
                               + (size_t)(c * 32 + r) * 128 + cc;
            #pragma unroll
            for (int q4 = 0; q4 < 4; q4++)
                s[q4] += *(const f32x4*)(src + q4 * 4);
        }
        #pragma unroll
        for (int q4 = 0; q4 < 4; q4++)
            *(f32x4*)&tile[r][cc + q4 * 4] = s[q4];
    }
    __syncthreads();
    {
        int e = t >> 1, dh = t & 1;
        ushort4 o[4];
        #pragma unroll
        for (int q4 = 0; q4 < 4; q4++) {
            o[q4].x = f2bf(tile[dh * 16 + q4 * 4 + 0][e]);
            o[q4].y = f2bf(tile[dh * 16 + q4 * 4 + 1][e]);
            o[q4].z = f2bf(tile[dh * 16 + q4 * 4 + 2][e]);
            o[q4].w = f2bf(tile[dh * 16 + q4 * 4 + 3][e]);
        }
        unsigned short* dst = kvTb + (size_t)bh * 16384 + e * 128 + c * 32 + dh * 16;
        #pragma unroll
        for (int q4 = 0; q4 < 4; q4++)
            ((ushort4*)dst)[q4] = o[q4];
    }
}

// ---------------- Kernel 3b: Q GEMM + fused out = sigmoid(q) . kv -------------
// GRID SWAPPED vs r6: (h=8 fastest, m=256). The 8 head-blocks of one m-tile are
// now dispatch-adjacent and co-resident -> xn A-tile read once through L2, not
// 8x across distant dispatches (r6 flaw: x=m fastest, A re-fetched per head).
__global__ __launch_bounds__(256, 3) void qkv_q_out(const unsigned short* __restrict__ xn,
                                                    const unsigned short* __restrict__ wT,
                                                    const unsigned short* __restrict__ kvTb,
                                                    float* __restrict__ out) {
    __shared__ unsigned short ShB[128 * CT_STRIDE];   // 34816 B
    const int t = threadIdx.x;
    const int w = t >> 6, l = t & 63;
    const int quad = l >> 4, ln16 = l & 15;
    const int m0 = blockIdx.y * 128;      // m-tile (slow)
    const int h = blockIdx.x;             // head   (fast)
    const int n0 = h * 128;               // q region columns
    const int b = m0 >> 13;
    const int bh = b * 8 + h;
    const int wm = (w >> 1) * 64, wn = (w & 1) * 64;

    f32x4 acc[4][4] = {};

    const unsigned short* aG = xn + (size_t)(m0 + w * 16 + (l >> 2)) * D_ + (l & 3) * 8;
    const unsigned short* bG = wT + (size_t)(n0 + w * 16 + (l >> 2)) * D_ + (l & 3) * 8;
    char* SB = (char*)ShB;

    for (int k0 = 0; k0 < 1024; k0 += 64) {
        #pragma unroll
        for (int s = 0; s < 2; s++) {
            gl_lds16(aG + k0 + s * 32,            SB + s * 8192 + w * 1024);
            gl_lds16(aG + 64 * D_ + k0 + s * 32,  SB + s * 8192 + 4096 + w * 1024);
            gl_lds16(bG + k0 + s * 32,            SB + 16384 + s * 8192 + w * 1024);
            gl_lds16(bG + 64 * D_ + k0 + s * 32,  SB + 16384 + s * 8192 + 4096 + w * 1024);
        }
        __syncthreads();
        #pragma unroll
        for (int s = 0; s < 2; s++) {
            const char* A0 = SB + s * 8192;
            const char* B0 = SB + 16384 + s * 8192;
            bf16x8 af[4], bfr[4];
            #pragma unroll
            for (int mi = 0; mi < 4; mi++)
                af[mi] = *(const bf16x8*)(A0 + (wm + mi * 16 + ln16) * 64 + quad * 16);
            #pragma unroll
            for (int ni = 0; ni < 4; ni++)
                bfr[ni] = *(const bf16x8*)(B0 + (wn + ni * 16 + ln16) * 64 + quad * 16);
            #pragma unroll
            for (int mi = 0; mi < 4; mi++)
                #pragma unroll
                for (int ni = 0; ni < 4; ni++)
                    acc[mi][ni] = __builtin_amdgcn_mfma_f32_16x16x32_bf16(af[mi], bfr[ni],
                                                                          acc[mi][ni], 0, 0, 0);
        }
        __syncthreads();
    }

    // epilogue phase 1: sigmoid -> bf16 -> ShB[tok][d], row stride 136 shorts
    #pragma unroll
    for (int mi = 0; mi < 4; mi++) {
        int tok0 = wm + mi * 16 + quad * 4;
        #pragma unroll
        for (int ni = 0; ni < 4; ni++) {
            int d = wn + ni * 16 + ln16;
            #pragma unroll
            for (int r = 0; r < 4; r++)
                ShB[(tok0 + r) * CT_STRIDE + d] = f2bf(fast_sigmoid(acc[mi][ni][r]));
        }
    }
    __syncthreads();

    // epilogue phase 2: out-tile = Q_lds . kvTb[bh]^T  (K = 128, 4 ks steps)
    const char* bB = (const char*)kvTb + (size_t)bh * 32768;
    f32x4 acc2[4][4] = {};
    #pragma unroll
    for (int ks = 0; ks < 4; ks++) {
        bf16x8 qa[4], kb[4];
        #pragma unroll
        for (int ni = 0; ni < 4; ni++)
            kb[ni] = *(const bf16x8*)(bB + (wn + ni * 16 + ln16) * 256 + ks * 64 + quad * 16);
        #pragma unroll
        for (int mi = 0; mi < 4; mi++)
            qa[mi] = *(const bf16x8*)((const char*)ShB + (wm + mi * 16 + ln16) * (CT_STRIDE * 2)
                                      + ks * 64 + quad * 16);
        #pragma unroll
        for (int mi = 0; mi < 4; mi++)
            #pragma unroll
            for (int ni = 0; ni < 4; ni++)
                acc2[mi][ni] = __builtin_amdgcn_mfma_f32_16x16x32_bf16(qa[mi], kb[ni],
                                                                       acc2[mi][ni], 0, 0, 0);
    }

    #pragma unroll
    for (int mi = 0; mi < 4; mi++) {
        #pragma unroll
        for (int r = 0; r < 4; r++) {
            int gm = m0 + wm + mi * 16 + quad * 4 + r;
            #pragma unroll
            for (int ni = 0; ni < 4; ni++) {
                int e = wn + ni * 16 + ln16;
                out[(size_t)gm * D_ + h * HD_ + e] = acc2[mi][ni][r];
            }
        }
    }
}

// ---------------- launch ----------------
extern "C" void kernel_launch(void* const* d_in, const int* in_sizes, int n_in,
                              void* d_out, int out_size, void* d_ws, size_t ws_size,
                              hipStream_t stream) {
    const float* x     = (const float*)d_in[0];
    const int*   mask  = (const int*)d_in[1];
    const float* w     = (const float*)d_in[2];
    const float* gamma = (const float*)d_in[3];
    const float* beta  = (const float*)d_in[4];
    float* out = (float*)d_out;
    char* ws = (char*)d_ws;

    // workspace layout (~276 MB)
    unsigned short* xn  = (unsigned short*)(ws + 0);              // 64 MB (live until qkv_q_out)
    unsigned short* wT  = (unsigned short*)(ws + 67108864ull);    // 6 MB
    float* kvp          = (float*)(ws + 73400320ull);             // 32 MB (old qws region)
    unsigned short* kT  = (unsigned short*)(ws + 140509184ull);   // 64 MB [bh][128][8192]
    unsigned short* vT  = (unsigned short*)(ws + 207618048ull);   // 64 MB [bh][128][8192]
    unsigned short* kvTb = (unsigned short*)(ws + 274726912ull);  // 1 MB bf16 [bh][e][d]

    hipLaunchKernelGGL(ln_kernel, dim3(M_TOT), dim3(64), 0, stream, x, gamma, beta, xn);
    hipLaunchKernelGGL(wt_kernel, dim3(48, 16), dim3(256), 0, stream, w, wT);
    hipLaunchKernelGGL(qkv_kv, dim3(16, M_TOT / 128), dim3(256), 0, stream,
                       xn, wT, mask, kT, vT);
    hipLaunchKernelGGL(kv_mfma, dim3(16, 32), dim3(256), 0, stream, kT, vT, kvp);
    hipLaunchKernelGGL(kvcvt, dim3(32, 4), dim3(256), 0, stream, kvp, kvTb);
    hipLaunchKernelGGL(qkv_q_out, dim3(8, M_TOT / 128), dim3(256), 0, stream,
                       xn, wT, kvTb, out);
}

// Round 8
// 507.837 us; speedup vs baseline: 1.0993x; 1.0152x over previous
//
#include <hip/hip_runtime.h>

// Problem constants
#define EPS 1e-5f
#define B_ 4
#define N_ 8192
#define D_ 1024
#define H_ 8
#define HD_ 128
#define M_TOT 32768   // B*N
#define NQKV 3072     // 3*D

typedef __bf16 bf16x8 __attribute__((ext_vector_type(8)));
typedef float f32x4 __attribute__((ext_vector_type(4)));

__device__ __forceinline__ float bf2f(unsigned short u) {
    unsigned int v = ((unsigned int)u) << 16;
    return __uint_as_float(v);
}
__device__ __forceinline__ unsigned short f2bf(float f) {
    unsigned int u = __float_as_uint(f);
    u += 0x7fffu + ((u >> 16) & 1u);   // RNE
    return (unsigned short)(u >> 16);
}

// fast activations: v_exp_f32 + v_rcp_f32 (~1e-6 rel err, saturates correctly)
__device__ __forceinline__ float fast_sigmoid(float v) {
    return __builtin_amdgcn_rcpf(1.0f + __expf(-v));
}
__device__ __forceinline__ float fast_tanh(float v) {
    return 1.0f - 2.0f * __builtin_amdgcn_rcpf(1.0f + __expf(2.0f * v));
}

// async global->LDS, 16B per lane; LDS dest is wave-uniform base + lane*16
__device__ __forceinline__ void gl_lds16(const void* g, void* l) {
    __builtin_amdgcn_global_load_lds(
        (const __attribute__((address_space(1))) unsigned int*)g,
        (__attribute__((address_space(3))) unsigned int*)l, 16, 0, 0);
}

// ---------------- Kernel 1: LayerNorm -> bf16 xn [32768][1024] ----------------
// One wave per row, 16 elems/lane, register-only shfl reduction.
__global__ __launch_bounds__(64) void ln_kernel(const float* __restrict__ x,
                                                const float* __restrict__ gamma,
                                                const float* __restrict__ beta,
                                                unsigned short* __restrict__ xn) {
    const int row = blockIdx.x;
    const int t = threadIdx.x;   // 0..63
    const float* xr = x + (size_t)row * D_;
    float4 xv[4];
    #pragma unroll
    for (int i = 0; i < 4; i++) xv[i] = ((const float4*)xr)[i * 64 + t];
    float s = 0.0f, s2 = 0.0f;
    #pragma unroll
    for (int i = 0; i < 4; i++) {
        s  += xv[i].x + xv[i].y + xv[i].z + xv[i].w;
        s2 += xv[i].x * xv[i].x + xv[i].y * xv[i].y
            + xv[i].z * xv[i].z + xv[i].w * xv[i].w;
    }
    #pragma unroll
    for (int off = 32; off > 0; off >>= 1) {
        s  += __shfl_down(s, off);
        s2 += __shfl_down(s2, off);
    }
    s = __shfl(s, 0);
    s2 = __shfl(s2, 0);
    const float mu = s * (1.0f / D_);
    const float var = s2 * (1.0f / D_) - mu * mu;
    const float rs = rsqrtf(var + EPS);
    unsigned short* xo = xn + (size_t)row * D_;
    #pragma unroll
    for (int i = 0; i < 4; i++) {
        float4 g  = ((const float4*)gamma)[i * 64 + t];
        float4 bt = ((const float4*)beta)[i * 64 + t];
        ushort4 o;
        o.x = f2bf((xv[i].x - mu) * rs * g.x + bt.x);
        o.y = f2bf((xv[i].y - mu) * rs * g.y + bt.y);
        o.z = f2bf((xv[i].z - mu) * rs * g.z + bt.z);
        o.w = f2bf((xv[i].w - mu) * rs * g.w + bt.w);
        ((ushort4*)xo)[i * 64 + t] = o;
    }
}

// ---------------- Kernel 2: transpose+cast w [1024][3072] -> wT bf16 [3072][1024]
__global__ __launch_bounds__(256) void wt_kernel(const float* __restrict__ w,
                                                 unsigned short* __restrict__ wT) {
    __shared__ float tile[64][65];
    const int n0 = blockIdx.x * 64;   // 48 blocks
    const int k0 = blockIdx.y * 64;   // 16 blocks
    const int t = threadIdx.x;
    const int tx = t & 63, ty = t >> 6;
    #pragma unroll
    for (int i = 0; i < 16; i++) {
        int r = i * 4 + ty;
        tile[r][tx] = w[(size_t)(k0 + r) * NQKV + n0 + tx];
    }
    __syncthreads();
    #pragma unroll
    for (int i = 0; i < 16; i++) {
        int r = i * 4 + ty;
        wT[(size_t)(n0 + r) * D_ + k0 + tx] = f2bf(tile[tx][r]);
    }
}

// ---------------- Kernel 3a: K/V GEMM (k,v regions only) + transpose epilogue -
// T1 XCD-chunk swizzle: 4096 blocks = 8 XCDs x (32 m-tiles x 16 n). Blocks with
// lin%8==c map to XCD c (round-robin heuristic) and share a contiguous m-range,
// so the 16 n-blocks reading one xn A-tile hit the SAME XCD L2 (was: spread
// over 8 non-coherent L2s -> 4x HBM over-fetch, FETCH=273MB vs 68MB ideal).
#define CT_STRIDE 136
__global__ __launch_bounds__(256, 3) void qkv_kv(const unsigned short* __restrict__ xn,
                                                 const unsigned short* __restrict__ wT,
                                                 const int* __restrict__ mask,
                                                 unsigned short* __restrict__ kT,
                                                 unsigned short* __restrict__ vT) {
    __shared__ unsigned short ShB[128 * CT_STRIDE];   // 34816 B; mainloop uses 32 KB
    const int t = threadIdx.x;
    const int w = t >> 6, l = t & 63;
    const int quad = l >> 4, ln16 = l & 15;
    // XCD swizzle (bijective: 4096 % 8 == 0)
    const int lin = blockIdx.x;
    const int xcd = lin & 7;
    const int idx = lin >> 3;             // 0..511 within XCD
    const int m0 = (xcd * 32 + (idx >> 4)) * 128;
    const int n0 = 1024 + (idx & 15) * 128;   // k/v regions only
    const int wm = (w >> 1) * 64, wn = (w & 1) * 64;

    f32x4 acc[4][4] = {};

    const unsigned short* aG = xn + (size_t)(m0 + w * 16 + (l >> 2)) * D_ + (l & 3) * 8;
    const unsigned short* bG = wT + (size_t)(n0 + w * 16 + (l >> 2)) * D_ + (l & 3) * 8;
    char* SB = (char*)ShB;

    for (int k0 = 0; k0 < 1024; k0 += 64) {
        #pragma unroll
        for (int s = 0; s < 2; s++) {
            gl_lds16(aG + k0 + s * 32,            SB + s * 8192 + w * 1024);
            gl_lds16(aG + 64 * D_ + k0 + s * 32,  SB + s * 8192 + 4096 + w * 1024);
            gl_lds16(bG + k0 + s * 32,            SB + 16384 + s * 8192 + w * 1024);
            gl_lds16(bG + 64 * D_ + k0 + s * 32,  SB + 16384 + s * 8192 + 4096 + w * 1024);
        }
        __syncthreads();
        #pragma unroll
        for (int s = 0; s < 2; s++) {
            const char* A0 = SB + s * 8192;
            const char* B0 = SB + 16384 + s * 8192;
            bf16x8 af[4], bfr[4];
            #pragma unroll
            for (int mi = 0; mi < 4; mi++)
                af[mi] = *(const bf16x8*)(A0 + (wm + mi * 16 + ln16) * 64 + quad * 16);
            #pragma unroll
            for (int ni = 0; ni < 4; ni++)
                bfr[ni] = *(const bf16x8*)(B0 + (wn + ni * 16 + ln16) * 64 + quad * 16);
            #pragma unroll
            for (int mi = 0; mi < 4; mi++)
                #pragma unroll
                for (int ni = 0; ni < 4; ni++)
                    acc[mi][ni] = __builtin_amdgcn_mfma_f32_16x16x32_bf16(af[mi], bfr[ni],
                                                                          acc[mi][ni], 0, 0, 0);
        }
        __syncthreads();
    }

    const int region = n0 >> 10;          // 1=k, 2=v
    const int cbase = n0 & 1023;
    // phase 1: store tile into LDS transposed [feat][tok], packed 4 toks/write
    #pragma unroll
    for (int mi = 0; mi < 4; mi++) {
        int tok0 = wm + mi * 16 + quad * 4;
        int mk0 = 0, mk1 = 0, mk2 = 0, mk3 = 0;
        if (region == 1) {
            mk0 = mask[m0 + tok0];
            mk1 = mask[m0 + tok0 + 1];
            mk2 = mask[m0 + tok0 + 2];
            mk3 = mask[m0 + tok0 + 3];
        }
        #pragma unroll
        for (int ni = 0; ni < 4; ni++) {
            int fl = wn + ni * 16 + ln16;
            float v0 = acc[mi][ni][0], v1 = acc[mi][ni][1];
            float v2 = acc[mi][ni][2], v3 = acc[mi][ni][3];
            if (region == 1) {
                v0 = mk0 ? 0.0f : fast_tanh(v0);
                v1 = mk1 ? 0.0f : fast_tanh(v1);
                v2 = mk2 ? 0.0f : fast_tanh(v2);
                v3 = mk3 ? 0.0f : fast_tanh(v3);
            }
            ushort4 pk;
            pk.x = f2bf(v0); pk.y = f2bf(v1); pk.z = f2bf(v2); pk.w = f2bf(v3);
            *(ushort4*)&ShB[fl * CT_STRIDE + tok0] = pk;   // 8B-aligned ds_write_b64
        }
    }
    __syncthreads();
    // phase 2: coalesced transposed global write (256B per feature row)
    unsigned short* dstT = (region == 1) ? kT : vT;
    const int h = cbase >> 7;          // block covers exactly one head
    const int b = m0 >> 13;
    const int ntok0 = m0 & 8191;
    #pragma unroll
    for (int p = 0; p < 8; p++) {
        int fl = p * 16 + (t >> 4);
        int tok = (t & 15) * 8;
        uint4 u = *(const uint4*)&ShB[fl * CT_STRIDE + tok];   // 16B-aligned b128
        *(uint4*)(dstT + ((size_t)(b * 8 + h) * 128 + fl) * 8192 + ntok0 + tok) = u;
    }
}

// ---------------- Kernel 4: kv partials (unchanged) ---------------------------
__global__ __launch_bounds__(256) void kv_mfma(const unsigned short* __restrict__ kT,
                                               const unsigned short* __restrict__ vT,
                                               float* __restrict__ kvp) {
    __shared__ __align__(16) char smem[32768];   // A 16KB + B 16KB
    char* AsB = smem;
    char* BsB = smem + 16384;
    const int t = threadIdx.x;
    const int w = t >> 6, l = t & 63;
    const int quad = l >> 4, ln16 = l & 15;
    const int bh = blockIdx.y;
    const int kc0 = blockIdx.x * 512;
    const int wm = (w >> 1) * 64, wn = (w & 1) * 64;

    f32x4 acc[4][4] = {};

    const size_t base = (size_t)bh * 128 * 8192;
    const int gsw = (l & 7) ^ (l >> 3);
    const unsigned short* aG = kT + base + (size_t)(w * 8 + (l >> 3)) * 8192 + kc0 + gsw * 8;
    const unsigned short* bG = vT + base + (size_t)(w * 8 + (l >> 3)) * 8192 + kc0 + gsw * 8;
    const int r7 = ln16 & 7;
    const int kb0 = ((quad ^ r7) << 4);
    const int kb1 = (((4 | quad) ^ r7) << 4);

    for (int kk = 0; kk < 512; kk += 64) {
        #pragma unroll
        for (int c = 0; c < 4; c++) {
            gl_lds16(aG + (size_t)(c * 32) * 8192 + kk, AsB + c * 4096 + w * 1024);
            gl_lds16(bG + (size_t)(c * 32) * 8192 + kk, BsB + c * 4096 + w * 1024);
        }
        __syncthreads();
        bf16x8 af[4][2], bfr[4][2];
        #pragma unroll
        for (int mi = 0; mi < 4; mi++) {
            const char* rp = AsB + (wm + mi * 16 + ln16) * 128;
            af[mi][0] = *(const bf16x8*)(rp + kb0);
            af[mi][1] = *(const bf16x8*)(rp + kb1);
        }
        #pragma unroll
        for (int ni = 0; ni < 4; ni++) {
            const char* rp = BsB + (wn + ni * 16 + ln16) * 128;
            bfr[ni][0] = *(const bf16x8*)(rp + kb0);
            bfr[ni][1] = *(const bf16x8*)(rp + kb1);
        }
        #pragma unroll
        for (int mi = 0; mi < 4; mi++)
            #pragma unroll
            for (int ni = 0; ni < 4; ni++) {
                acc[mi][ni] = __builtin_amdgcn_mfma_f32_16x16x32_bf16(af[mi][0], bfr[ni][0],
                                                                      acc[mi][ni], 0, 0, 0);
                acc[mi][ni] = __builtin_amdgcn_mfma_f32_16x16x32_bf16(af[mi][1], bfr[ni][1],
                                                                      acc[mi][ni], 0, 0, 0);
            }
        __syncthreads();
    }

    float* dst = kvp + ((size_t)blockIdx.x * 32 + bh) * (HD_ * HD_);
    #pragma unroll
    for (int mi = 0; mi < 4; mi++) {
        #pragma unroll
        for (int r = 0; r < 4; r++) {
            int d = wm + mi * 16 + quad * 4 + r;
            #pragma unroll
            for (int ni = 0; ni < 4; ni++) {
                int e = wn + ni * 16 + ln16;
                dst[d * HD_ + e] = acc[mi][ni][r];
            }
        }
    }
}

// ---------------- Kernel 4b: reduce 16 partials + transpose + cast -> kvTb ----
__global__ __launch_bounds__(256) void kvcvt(const float* __restrict__ kvp,
                                             unsigned short* __restrict__ kvTb) {
    __shared__ float tile[32][132];
    const int bh = blockIdx.x;
    const int c = blockIdx.y;     // d-chunk of 32
    const int t = threadIdx.x;
    {
        int r = t >> 3, cc = (t & 7) * 16;
        f32x4 s[4] = {};
        for (int p = 0; p < 16; p++) {
            const float* src = kvp + ((size_t)p * 32 + bh) * (HD_ * HD_)
                               + (size_t)(c * 32 + r) * 128 + cc;
            #pragma unroll
            for (int q4 = 0; q4 < 4; q4++)
                s[q4] += *(const f32x4*)(src + q4 * 4);
        }
        #pragma unroll
        for (int q4 = 0; q4 < 4; q4++)
            *(f32x4*)&tile[r][cc + q4 * 4] = s[q4];
    }
    __syncthreads();
    {
        int e = t >> 1, dh = t & 1;
        ushort4 o[4];
        #pragma unroll
        for (int q4 = 0; q4 < 4; q4++) {
            o[q4].x = f2bf(tile[dh * 16 + q4 * 4 + 0][e]);
            o[q4].y = f2bf(tile[dh * 16 + q4 * 4 + 1][e]);
            o[q4].z = f2bf(tile[dh * 16 + q4 * 4 + 2][e]);
            o[q4].w = f2bf(tile[dh * 16 + q4 * 4 + 3][e]);
        }
        unsigned short* dst = kvTb + (size_t)bh * 16384 + e * 128 + c * 32 + dh * 16;
        #pragma unroll
        for (int q4 = 0; q4 < 4; q4++)
            ((ushort4*)dst)[q4] = o[q4];
    }
}

// ---------------- Kernel 3b: Q GEMM + fused out = sigmoid(q) . kv -------------
// T1 XCD-chunk swizzle: 2048 blocks = 8 XCDs x (32 m-tiles x 8 heads); the 8
// head-blocks sharing one xn A-tile land on the same XCD L2, h fastest within.
__global__ __launch_bounds__(256, 3) void qkv_q_out(const unsigned short* __restrict__ xn,
                                                    const unsigned short* __restrict__ wT,
                                                    const unsigned short* __restrict__ kvTb,
                                                    float* __restrict__ out) {
    __shared__ unsigned short ShB[128 * CT_STRIDE];   // 34816 B
    const int t = threadIdx.x;
    const int w = t >> 6, l = t & 63;
    const int quad = l >> 4, ln16 = l & 15;
    // XCD swizzle (bijective: 2048 % 8 == 0)
    const int lin = blockIdx.x;
    const int xcd = lin & 7;
    const int idx = lin >> 3;             // 0..255 within XCD
    const int m0 = (xcd * 32 + (idx >> 3)) * 128;
    const int h = idx & 7;
    const int n0 = h * 128;               // q region columns
    const int b = m0 >> 13;
    const int bh = b * 8 + h;
    const int wm = (w >> 1) * 64, wn = (w & 1) * 64;

    f32x4 acc[4][4] = {};

    const unsigned short* aG = xn + (size_t)(m0 + w * 16 + (l >> 2)) * D_ + (l & 3) * 8;
    const unsigned short* bG = wT + (size_t)(n0 + w * 16 + (l >> 2)) * D_ + (l & 3) * 8;
    char* SB = (char*)ShB;

    for (int k0 = 0; k0 < 1024; k0 += 64) {
        #pragma unroll
        for (int s = 0; s < 2; s++) {
            gl_lds16(aG + k0 + s * 32,            SB + s * 8192 + w * 1024);
            gl_lds16(aG + 64 * D_ + k0 + s * 32,  SB + s * 8192 + 4096 + w * 1024);
            gl_lds16(bG + k0 + s * 32,            SB + 16384 + s * 8192 + w * 1024);
            gl_lds16(bG + 64 * D_ + k0 + s * 32,  SB + 16384 + s * 8192 + 4096 + w * 1024);
        }
        __syncthreads();
        #pragma unroll
        for (int s = 0; s < 2; s++) {
            const char* A0 = SB + s * 8192;
            const char* B0 = SB + 16384 + s * 8192;
            bf16x8 af[4], bfr[4];
            #pragma unroll
            for (int mi = 0; mi < 4; mi++)
                af[mi] = *(const bf16x8*)(A0 + (wm + mi * 16 + ln16) * 64 + quad * 16);
            #pragma unroll
            for (int ni = 0; ni < 4; ni++)
                bfr[ni] = *(const bf16x8*)(B0 + (wn + ni * 16 + ln16) * 64 + quad * 16);
            #pragma unroll
            for (int mi = 0; mi < 4; mi++)
                #pragma unroll
                for (int ni = 0; ni < 4; ni++)
                    acc[mi][ni] = __builtin_amdgcn_mfma_f32_16x16x32_bf16(af[mi], bfr[ni],
                                                                          acc[mi][ni], 0, 0, 0);
        }
        __syncthreads();
    }

    // epilogue phase 1: sigmoid -> bf16 -> ShB[tok][d], row stride 136 shorts
    #pragma unroll
    for (int mi = 0; mi < 4; mi++) {
        int tok0 = wm + mi * 16 + quad * 4;
        #pragma unroll
        for (int ni = 0; ni < 4; ni++) {
            int d = wn + ni * 16 + ln16;
            #pragma unroll
            for (int r = 0; r < 4; r++)
                ShB[(tok0 + r) * CT_STRIDE + d] = f2bf(fast_sigmoid(acc[mi][ni][r]));
        }
    }
    __syncthreads();

    // epilogue phase 2: out-tile = Q_lds . kvTb[bh]^T  (K = 128, 4 ks steps)
    const char* bB = (const char*)kvTb + (size_t)bh * 32768;
    f32x4 acc2[4][4] = {};
    #pragma unroll
    for (int ks = 0; ks < 4; ks++) {
        bf16x8 qa[4], kb[4];
        #pragma unroll
        for (int ni = 0; ni < 4; ni++)
            kb[ni] = *(const bf16x8*)(bB + (wn + ni * 16 + ln16) * 256 + ks * 64 + quad * 16);
        #pragma unroll
        for (int mi = 0; mi < 4; mi++)
            qa[mi] = *(const bf16x8*)((const char*)ShB + (wm + mi * 16 + ln16) * (CT_STRIDE * 2)
                                      + ks * 64 + quad * 16);
        #pragma unroll
        for (int mi = 0; mi < 4; mi++)
            #pragma unroll
            for (int ni = 0; ni < 4; ni++)
                acc2[mi][ni] = __builtin_amdgcn_mfma_f32_16x16x32_bf16(qa[mi], kb[ni],
                                                                       acc2[mi][ni], 0, 0, 0);
    }

    #pragma unroll
    for (int mi = 0; mi < 4; mi++) {
        #pragma unroll
        for (int r = 0; r < 4; r++) {
            int gm = m0 + wm + mi * 16 + quad * 4 + r;
            #pragma unroll
            for (int ni = 0; ni < 4; ni++) {
                int e = wn + ni * 16 + ln16;
                out[(size_t)gm * D_ + h * HD_ + e] = acc2[mi][ni][r];
            }
        }
    }
}

// ---------------- launch ----------------
extern "C" void kernel_launch(void* const* d_in, const int* in_sizes, int n_in,
                              void* d_out, int out_size, void* d_ws, size_t ws_size,
                              hipStream_t stream) {
    const float* x     = (const float*)d_in[0];
    const int*   mask  = (const int*)d_in[1];
    const float* w     = (const float*)d_in[2];
    const float* gamma = (const float*)d_in[3];
    const float* beta  = (const float*)d_in[4];
    float* out = (float*)d_out;
    char* ws = (char*)d_ws;

    // workspace layout (~276 MB)
    unsigned short* xn  = (unsigned short*)(ws + 0);              // 64 MB (live until qkv_q_out)
    unsigned short* wT  = (unsigned short*)(ws + 67108864ull);    // 6 MB
    float* kvp          = (float*)(ws + 73400320ull);             // 32 MB (old qws region)
    unsigned short* kT  = (unsigned short*)(ws + 140509184ull);   // 64 MB [bh][128][8192]
    unsigned short* vT  = (unsigned short*)(ws + 207618048ull);   // 64 MB [bh][128][8192]
    unsigned short* kvTb = (unsigned short*)(ws + 274726912ull);  // 1 MB bf16 [bh][e][d]

    hipLaunchKernelGGL(ln_kernel, dim3(M_TOT), dim3(64), 0, stream, x, gamma, beta, xn);
    hipLaunchKernelGGL(wt_kernel, dim3(48, 16), dim3(256), 0, stream, w, wT);
    hipLaunchKernelGGL(qkv_kv, dim3(4096), dim3(256), 0, stream,
                       xn, wT, mask, kT, vT);
    hipLaunchKernelGGL(kv_mfma, dim3(16, 32), dim3(256), 0, stream, kT, vT, kvp);
    hipLaunchKernelGGL(kvcvt, dim3(32, 4), dim3(256), 0, stream, kvp, kvTb);
    hipLaunchKernelGGL(qkv_q_out, dim3(2048), dim3(256), 0, stream,
                       xn, wT, kvTb, out);
}